// Round 8
// baseline (195.702 us; speedup 1.0000x reference)
//
#include <hip/hip_runtime.h>
#include <hip/hip_bf16.h>
#include <math.h>

typedef __bf16 bf16_t;
typedef bf16_t bf16x4 __attribute__((ext_vector_type(4)));
typedef bf16_t bf16x8 __attribute__((ext_vector_type(8)));
typedef float f32x4 __attribute__((ext_vector_type(4)));

#define SEQ 2048
#define BATCH 2
#define NHEAD 16
#define DK 64
#define DMODEL 1024

#define GLOAD16(gsrc, ldst)                                                        \
    __builtin_amdgcn_global_load_lds(                                              \
        (const __attribute__((address_space(1))) void*)(gsrc),                     \
        (__attribute__((address_space(3))) void*)(ldst), 16, 0, 0)

__device__ __forceinline__ float exp2_hw(float x) {
#if __has_builtin(__builtin_amdgcn_exp2f)
    return __builtin_amdgcn_exp2f(x);
#else
    float r; asm("v_exp_f32 %0, %1" : "=v"(r) : "v"(x)); return r;
#endif
}

// ---------------- fused prep: cvt x -> bf16 | transpose 4x W -> bf16 | rope table ----
__global__ __launch_bounds__(256)
void prep_kernel(const float* __restrict__ x, bf16_t* __restrict__ y,
                 const float* __restrict__ W0, const float* __restrict__ W1,
                 const float* __restrict__ W2, const float* __restrict__ W3,
                 bf16_t* __restrict__ Wt, float2* __restrict__ cs) {
    __shared__ float t[32][33];
    const int id = blockIdx.x, tid = threadIdx.x;
    if (id < 4096) {                               // cvt x (4096 blocks)
        int i = (id * 256 + tid) * 4;
        float4 v = *reinterpret_cast<const float4*>(x + i);
        bf16x4 o = { (bf16_t)v.x, (bf16_t)v.y, (bf16_t)v.z, (bf16_t)v.w };
        *reinterpret_cast<bf16x4*>(y + i) = o;
    } else if (id < 8192) {                        // transpose W (4096 blocks)
        const int id2 = id - 4096;
        const int z = id2 >> 10, rem = id2 & 1023;
        const int n0 = (rem & 31) * 32, k0 = ((rem >> 5) & 31) * 32;
        const int tx = tid & 31, ty = tid >> 5;    // 32 x 8
        const float* W = (z == 0) ? W0 : (z == 1) ? W1 : (z == 2) ? W2 : W3;
        bf16_t* out = Wt + ((size_t)z << 20);
#pragma unroll
        for (int i = 0; i < 32; i += 8)
            t[ty + i][tx] = W[(size_t)(k0 + ty + i) * DMODEL + n0 + tx];
        __syncthreads();
#pragma unroll
        for (int i = 0; i < 32; i += 8)
            out[(size_t)(n0 + ty + i) * DMODEL + k0 + tx] = (bf16_t)t[tx][ty + i];
    } else {                                       // rope table (256 blocks)
        int idx = (id - 8192) * 256 + tid;         // SEQ*32
        int j = idx & 31, s = idx >> 5;
        float inv = powf(10000.0f, -(float)j / 32.0f);
        float ang = (float)s * inv;
        cs[idx] = make_float2(cosf(ang), sinf(ang));
    }
}

// ---------------- GEMM core: 128 x (NF*32) tile, BK=32, 3-deep prefetch ----------------
template<int NF>
__device__ __forceinline__ void gemm_core(const bf16_t* __restrict__ A,
                                          const bf16_t* __restrict__ Bt,
                                          int m0, int n0,
                                          bf16_t* As, bf16_t* Bs,
                                          f32x4 (&acc)[4][NF]) {
    const int tid = threadIdx.x, lane = tid & 63, wid = tid >> 6;
    const int wr = wid >> 1, wc = wid & 1;
    const int lm = lane & 15, lq = lane >> 4;
    constexpr int BROWS = NF * 32;
    constexpr int NT = DMODEL / 32;

    const int r_in = lane >> 2;                                  // 0..15
    const int csw  = (((lane & 3) ^ ((lane >> 3) & 3)) << 3);    // src col (elems)
    const bf16_t* Ag = A  + (size_t)(m0 + 32 * wid + r_in) * DMODEL + csw;
    const bf16_t* Bg = Bt + (size_t)(n0 + (NF * 8) * wid + r_in) * DMODEL + csw;
    const int cswr = ((lq ^ ((lm >> 1) & 3)) << 4);

    auto stage = [&](int t, int buf) {
        const int k0 = t * 32;
        bf16_t* a = As + buf * (128 * 32) + 32 * wid * 32;
        bf16_t* b = Bs + buf * (BROWS * 32) + (NF * 8) * wid * 32;
        GLOAD16(Ag + k0,               a);
        GLOAD16(Ag + 16 * DMODEL + k0, a + 16 * 32);
        GLOAD16(Bg + k0,               b);
        if constexpr (NF == 4) GLOAD16(Bg + 16 * DMODEL + k0, b + 16 * 32);
    };

    stage(0, 0);
    stage(1, 1);
    int cb = 0;
    for (int t = 0; t < NT; ++t) {
        if (t + 2 < NT) {
            int sb = cb + 2; if (sb >= 3) sb -= 3;
            stage(t + 2, sb);
            if constexpr (NF == 4) asm volatile("s_waitcnt vmcnt(8)" ::: "memory");
            else                   asm volatile("s_waitcnt vmcnt(6)" ::: "memory");
        } else if (t + 1 < NT) {
            if constexpr (NF == 4) asm volatile("s_waitcnt vmcnt(4)" ::: "memory");
            else                   asm volatile("s_waitcnt vmcnt(3)" ::: "memory");
        } else {
            asm volatile("s_waitcnt vmcnt(0)" ::: "memory");
        }
        __builtin_amdgcn_s_barrier();

        const char* pAs = (const char*)(As + cb * (128 * 32));
        const char* pBs = (const char*)(Bs + cb * (BROWS * 32));
        bf16x8 af[4], bfr[NF];
#pragma unroll
        for (int mf = 0; mf < 4; ++mf)
            af[mf] = *reinterpret_cast<const bf16x8*>(pAs + (wr * 64 + mf * 16 + lm) * 64 + cswr);
#pragma unroll
        for (int nf = 0; nf < NF; ++nf)
            bfr[nf] = *reinterpret_cast<const bf16x8*>(pBs + (wc * (NF * 16) + nf * 16 + lm) * 64 + cswr);
#pragma unroll
        for (int mf = 0; mf < 4; ++mf)
#pragma unroll
            for (int nf = 0; nf < NF; ++nf)
                acc[mf][nf] = __builtin_amdgcn_mfma_f32_16x16x32_bf16(af[mf], bfr[nf], acc[mf][nf], 0, 0, 0);

        asm volatile("" ::: "memory");
        __builtin_amdgcn_s_barrier();
        if (++cb == 3) cb = 0;
    }
}

// ---------------- fused QKV projections: 768 blocks (XCD-swizzled) ----------------
__global__ __launch_bounds__(256)
void gemm_qkv_kernel(const bf16_t* __restrict__ xb, const bf16_t* __restrict__ wtqk,
                     const bf16_t* __restrict__ wtv,
                     const float* __restrict__ bq, const float* __restrict__ bk,
                     const float* __restrict__ bv,
                     bf16_t* __restrict__ qb, bf16_t* __restrict__ kb,
                     bf16_t* __restrict__ vtb, const float2* __restrict__ cs) {
    __shared__ bf16_t As[3 * 128 * 32];
    __shared__ bf16_t Bs[3 * 128 * 32];
    const int tid = threadIdx.x, lane = tid & 63, wid = tid >> 6;
    const int wr = wid >> 1, wc = wid & 1;
    const int lm = lane & 15, lq = lane >> 4;
    const int orig = blockIdx.x;
    const int id = (orig & 7) * 96 + (orig >> 3);   // bijective XCD swizzle (768 = 8*96)
    f32x4 acc[4][4] = {};

    if (id < 512) {
        const int m0 = (id >> 4) * 128, n0 = (id & 15) * 128;
        gemm_core<4>(xb, wtqk, m0, n0, As, Bs, acc);
        const bool is_k = (n0 >= 1024);
        const float* bs = is_k ? bk : bq;
        bf16_t* C = is_k ? kb : qb;
        const int cb = (is_k ? n0 - 1024 : n0) + wc * 64;
        const float b0 = bs[cb + lm],      b1 = bs[cb + 16 + lm];
        const float b2 = bs[cb + 32 + lm], b3 = bs[cb + 48 + lm];
#pragma unroll
        for (int mf = 0; mf < 4; ++mf)
#pragma unroll
            for (int i = 0; i < 4; ++i) {
                const int row = m0 + wr * 64 + mf * 16 + lq * 4 + i;
                const int s = row & (SEQ - 1);
                const float2 cs0 = cs[s * 32 + lm];
                const float2 cs1 = cs[s * 32 + 16 + lm];
                const float a0 = acc[mf][0][i] + b0, a1 = acc[mf][1][i] + b1;
                const float a2 = acc[mf][2][i] + b2, a3 = acc[mf][3][i] + b3;
                bf16_t* p = C + (size_t)row * DMODEL + cb;
                p[lm]      = (bf16_t)(a0 * cs0.x - a2 * cs0.y);
                p[16 + lm] = (bf16_t)(a1 * cs1.x - a3 * cs1.y);
                p[32 + lm] = (bf16_t)(a2 * cs0.x + a0 * cs0.y);
                p[48 + lm] = (bf16_t)(a3 * cs1.x + a1 * cs1.y);
            }
    } else {
        const int id2 = id - 512;
        const int m0 = (id2 & 7) * 128, n0 = (id2 >> 3) * 128;
        gemm_core<4>(wtv, xb, m0, n0, As, Bs, acc);
#pragma unroll
        for (int mf = 0; mf < 4; ++mf)
#pragma unroll
            for (int i = 0; i < 4; ++i) {
                const int row = m0 + wr * 64 + mf * 16 + lq * 4 + i;
                const float brow = bv[row];
#pragma unroll
                for (int nf = 0; nf < 4; ++nf) {
                    const int col = n0 + wc * 64 + nf * 16 + lm;
                    vtb[(size_t)row * 4096 + col] = (bf16_t)(acc[mf][nf][i] + brow);
                }
            }
    }
}

// ---------------- output projection: 128x64 tile, 512 blocks (XCD-swizzled) ----------
__global__ __launch_bounds__(256)
void gemm_out_kernel(const bf16_t* __restrict__ A, const bf16_t* __restrict__ Bt,
                     const float* __restrict__ bias, float* __restrict__ C) {
    __shared__ bf16_t As[3 * 128 * 32];
    __shared__ bf16_t Bs[3 * 64 * 32];
    const int tid = threadIdx.x, lane = tid & 63, wid = tid >> 6;
    const int wr = wid >> 1, wc = wid & 1;
    const int lm = lane & 15, lq = lane >> 4;
    const int orig = blockIdx.x;
    const int id = (orig & 7) * 64 + (orig >> 3);   // bijective XCD swizzle (512 = 8*64)
    const int m0 = (id >> 4) * 128, n0 = (id & 15) * 64;
    f32x4 acc[4][2] = {};
    gemm_core<2>(A, Bt, m0, n0, As, Bs, acc);
#pragma unroll
    for (int nf = 0; nf < 2; ++nf) {
        const int col = n0 + wc * 32 + nf * 16 + lm;
        const float bcol = bias[col];
#pragma unroll
        for (int mf = 0; mf < 4; ++mf)
#pragma unroll
            for (int i = 0; i < 4; ++i) {
                const int row = m0 + wr * 64 + mf * 16 + lq * 4 + i;
                C[(size_t)row * DMODEL + col] = acc[mf][nf][i] + bcol;
            }
    }
}

// ---------------- flash attention: NO LDS, NO barriers — direct L1/L2 fragment loads ---
// 4 waves x 32 q-rows, fully independent waves. K row permutation folded into pointer
// math (row g(t,lm) = tofs[t] + 8*(lm>>2) + (lm&3)) so QK's C-layout = PV's B-layout:
// P never leaves registers. Denominator via ones-MFMA. Static max MS in acc-init.
__global__ __launch_bounds__(256)
void attn_kernel(const bf16_t* __restrict__ q, const bf16_t* __restrict__ k,
                 const bf16_t* __restrict__ vt, bf16_t* __restrict__ attnout) {
    const int tid = threadIdx.x, lane = tid & 63, wid = tid >> 6;
    const int lm = lane & 15, lq = lane >> 4;
    const int bh = blockIdx.y, b = bh >> 4, h = bh & 15;
    const int qrow0 = blockIdx.x * 128 + wid * 32;
    const float MS = 20.0f;

    // Q fragments (B-operand), 2 sets of 16 rows, pre-scaled by (1/sqrt(64))*log2(e)
    const bf16_t* qA = q + ((size_t)(b * SEQ + qrow0 + lm) * NHEAD + h) * DK + lq * 8;
    const bf16_t* qB = qA + (size_t)16 * NHEAD * DK;
    bf16x8 aqA0 = *reinterpret_cast<const bf16x8*>(qA);
    bf16x8 aqA1 = *reinterpret_cast<const bf16x8*>(qA + 32);
    bf16x8 aqB0 = *reinterpret_cast<const bf16x8*>(qB);
    bf16x8 aqB1 = *reinterpret_cast<const bf16x8*>(qB + 32);
#pragma unroll
    for (int j = 0; j < 8; ++j) {
        aqA0[j] = (bf16_t)((float)aqA0[j] * 0.18033688f);
        aqA1[j] = (bf16_t)((float)aqA1[j] * 0.18033688f);
        aqB0[j] = (bf16_t)((float)aqB0[j] * 0.18033688f);
        aqB1[j] = (bf16_t)((float)aqB1[j] * 0.18033688f);
    }
    const bf16_t one = (bf16_t)1.0f;
    const bf16x8 ones = { one, one, one, one, one, one, one, one };
    const f32x4 cinit = { -MS, -MS, -MS, -MS };

    // per-lane K pointers for the 4 QK sub-tiles (permuted rows, a1 = +32 elems)
    const int rbase = 8 * (lm >> 2) + (lm & 3);
    const int tofs[4] = { 0, 4, 32, 36 };
    const bf16_t* kp[4];
#pragma unroll
    for (int t = 0; t < 4; ++t)
        kp[t] = k + ((size_t)(b * SEQ + tofs[t] + rbase) * NHEAD + h) * DK + lq * 8;
    // per-lane V pointers for the 4 PV sub-tiles (v1 = +32 cols)
    const bf16_t* vp[4];
#pragma unroll
    for (int nf = 0; nf < 4; ++nf)
        vp[nf] = vt + (size_t)(h * DK + nf * 16 + lm) * 4096 + b * SEQ + lq * 8;

    f32x4 OA[4] = {}, OB[4] = {};
    f32x4 olA = {}, olB = {};

    // K fragment prefetch (tile 0)
    bf16x8 kf0[4], kf1[4];
#pragma unroll
    for (int t = 0; t < 4; ++t) {
        kf0[t] = *reinterpret_cast<const bf16x8*>(kp[t]);
        kf1[t] = *reinterpret_cast<const bf16x8*>(kp[t] + 32);
    }

    for (int kb = 0; kb < SEQ; kb += 64) {
        // V fragment loads for this tile (latency hidden under QK + exp2)
        bf16x8 vf0[4], vf1[4];
#pragma unroll
        for (int nf = 0; nf < 4; ++nf) {
            vf0[nf] = *reinterpret_cast<const bf16x8*>(vp[nf] + kb);
            vf1[nf] = *reinterpret_cast<const bf16x8*>(vp[nf] + kb + 32);
        }

        // QK^T on current K fragments
        f32x4 stA[4], stB[4];
        __builtin_amdgcn_s_setprio(1);
#pragma unroll
        for (int t = 0; t < 4; ++t) {
            f32x4 sA = __builtin_amdgcn_mfma_f32_16x16x32_bf16(kf0[t], aqA0, cinit, 0, 0, 0);
            sA = __builtin_amdgcn_mfma_f32_16x16x32_bf16(kf1[t], aqA1, sA, 0, 0, 0);
            f32x4 sB = __builtin_amdgcn_mfma_f32_16x16x32_bf16(kf0[t], aqB0, cinit, 0, 0, 0);
            sB = __builtin_amdgcn_mfma_f32_16x16x32_bf16(kf1[t], aqB1, sB, 0, 0, 0);
            stA[t] = sA; stB[t] = sB;
        }
        __builtin_amdgcn_s_setprio(0);

        // prefetch next tile's K fragments (latency hidden under exp2 + PV)
        if (kb + 64 < SEQ) {
            const size_t adv = (size_t)(kb + 64) * NHEAD * DK;
#pragma unroll
            for (int t = 0; t < 4; ++t) {
                kf0[t] = *reinterpret_cast<const bf16x8*>(kp[t] + adv);
                kf1[t] = *reinterpret_cast<const bf16x8*>(kp[t] + adv + 32);
            }
        }

        // exp2 + pack: P already in PV B-frag order
        bf16x8 paA0, paA1, paB0, paB1;
#pragma unroll
        for (int t = 0; t < 2; ++t)
#pragma unroll
            for (int i = 0; i < 4; ++i) {
                paA0[4 * t + i] = (bf16_t)exp2_hw(stA[t][i]);
                paA1[4 * t + i] = (bf16_t)exp2_hw(stA[t + 2][i]);
                paB0[4 * t + i] = (bf16_t)exp2_hw(stB[t][i]);
                paB1[4 * t + i] = (bf16_t)exp2_hw(stB[t + 2][i]);
            }

        // PV on this tile's V fragments
        __builtin_amdgcn_s_setprio(1);
#pragma unroll
        for (int nf = 0; nf < 4; ++nf) {
            f32x4 oA = OA[nf], oB = OB[nf];
            oA = __builtin_amdgcn_mfma_f32_16x16x32_bf16(vf0[nf], paA0, oA, 0, 0, 0);
            oA = __builtin_amdgcn_mfma_f32_16x16x32_bf16(vf1[nf], paA1, oA, 0, 0, 0);
            oB = __builtin_amdgcn_mfma_f32_16x16x32_bf16(vf0[nf], paB0, oB, 0, 0, 0);
            oB = __builtin_amdgcn_mfma_f32_16x16x32_bf16(vf1[nf], paB1, oB, 0, 0, 0);
            OA[nf] = oA; OB[nf] = oB;
        }
        olA = __builtin_amdgcn_mfma_f32_16x16x32_bf16(ones, paA0, olA, 0, 0, 0);
        olA = __builtin_amdgcn_mfma_f32_16x16x32_bf16(ones, paA1, olA, 0, 0, 0);
        olB = __builtin_amdgcn_mfma_f32_16x16x32_bf16(ones, paB0, olB, 0, 0, 0);
        olB = __builtin_amdgcn_mfma_f32_16x16x32_bf16(ones, paB1, olB, 0, 0, 0);
        __builtin_amdgcn_s_setprio(0);
    }

    const float invA = 1.0f / olA[0];
    const float invB = 1.0f / olB[0];
    bf16_t* obA = attnout + ((size_t)(b * SEQ + qrow0 + lm) * NHEAD + h) * DK;
    bf16_t* obB = obA + (size_t)16 * NHEAD * DK;
#pragma unroll
    for (int nf = 0; nf < 4; ++nf) {
        bf16x4 cA = { (bf16_t)(OA[nf][0] * invA), (bf16_t)(OA[nf][1] * invA),
                      (bf16_t)(OA[nf][2] * invA), (bf16_t)(OA[nf][3] * invA) };
        bf16x4 cB = { (bf16_t)(OB[nf][0] * invB), (bf16_t)(OB[nf][1] * invB),
                      (bf16_t)(OB[nf][2] * invB), (bf16_t)(OB[nf][3] * invB) };
        *reinterpret_cast<bf16x4*>(obA + nf * 16 + lq * 4) = cA;
        *reinterpret_cast<bf16x4*>(obB + nf * 16 + lq * 4) = cB;
    }
}

extern "C" void kernel_launch(void* const* d_in, const int* in_sizes, int n_in,
                              void* d_out, int out_size, void* d_ws, size_t ws_size,
                              hipStream_t stream) {
    const float* x  = (const float*)d_in[0];
    const float* Wq = (const float*)d_in[1];
    const float* bq = (const float*)d_in[2];
    const float* Wk = (const float*)d_in[3];
    const float* bk = (const float*)d_in[4];
    const float* Wv = (const float*)d_in[5];
    const float* bv = (const float*)d_in[6];
    const float* Wo = (const float*)d_in[7];
    const float* bo = (const float*)d_in[8];
    float* out = (float*)d_out;

    char* ws = (char*)d_ws;
    bf16_t* xb  = (bf16_t*)(ws);                       // 8MB (x bf16; reused as attn-out)
    bf16_t* wtq = (bf16_t*)(ws + ((size_t)8  << 20));  // 4 x 2MB transposed weights (q,k,v,o)
    bf16_t* wtv = wtq + (2 << 20);
    bf16_t* wto = wtq + (3 << 20);
    bf16_t* qb  = (bf16_t*)(ws + ((size_t)16 << 20));  // 8MB
    bf16_t* kb  = (bf16_t*)(ws + ((size_t)24 << 20));  // 8MB
    bf16_t* vtb = (bf16_t*)(ws + ((size_t)32 << 20));  // 8MB, [1024][4096]
    float2* csT = (float2*)(ws + ((size_t)40 << 20));  // 512KB
    bf16_t* aob = xb;

    prep_kernel<<<8448, 256, 0, stream>>>(x, xb, Wq, Wk, Wv, Wo, wtq, csT);
    gemm_qkv_kernel<<<768, 256, 0, stream>>>(xb, wtq, wtv, bq, bk, bv, qb, kb, vtb, csT);
    attn_kernel<<<dim3(16, 32), 256, 0, stream>>>(qb, kb, vtb, aob);
    gemm_out_kernel<<<512, 256, 0, stream>>>(aob, wto, bo, out);
}

// Round 9
// 123.046 us; speedup vs baseline: 1.5905x; 1.5905x over previous
//
#include <hip/hip_runtime.h>
#include <hip/hip_bf16.h>
#include <math.h>

typedef __bf16 bf16_t;
typedef bf16_t bf16x4 __attribute__((ext_vector_type(4)));
typedef bf16_t bf16x8 __attribute__((ext_vector_type(8)));
typedef float f32x4 __attribute__((ext_vector_type(4)));

#define SEQ 2048
#define BATCH 2
#define NHEAD 16
#define DK 64
#define DMODEL 1024

#define GLOAD16(gsrc, ldst)                                                        \
    __builtin_amdgcn_global_load_lds(                                              \
        (const __attribute__((address_space(1))) void*)(gsrc),                     \
        (__attribute__((address_space(3))) void*)(ldst), 16, 0, 0)

__device__ __forceinline__ float exp2_hw(float x) {
#if __has_builtin(__builtin_amdgcn_exp2f)
    return __builtin_amdgcn_exp2f(x);
#else
    float r; asm("v_exp_f32 %0, %1" : "=v"(r) : "v"(x)); return r;
#endif
}

// ---------------- fused prep: cvt x -> bf16 | transpose 4x W -> bf16 | rope table ----
__global__ __launch_bounds__(256)
void prep_kernel(const float* __restrict__ x, bf16_t* __restrict__ y,
                 const float* __restrict__ W0, const float* __restrict__ W1,
                 const float* __restrict__ W2, const float* __restrict__ W3,
                 bf16_t* __restrict__ Wt, float2* __restrict__ cs) {
    __shared__ float t[32][33];
    const int id = blockIdx.x, tid = threadIdx.x;
    if (id < 4096) {                               // cvt x (4096 blocks)
        int i = (id * 256 + tid) * 4;
        float4 v = *reinterpret_cast<const float4*>(x + i);
        bf16x4 o = { (bf16_t)v.x, (bf16_t)v.y, (bf16_t)v.z, (bf16_t)v.w };
        *reinterpret_cast<bf16x4*>(y + i) = o;
    } else if (id < 8192) {                        // transpose W (4096 blocks)
        const int id2 = id - 4096;
        const int z = id2 >> 10, rem = id2 & 1023;
        const int n0 = (rem & 31) * 32, k0 = ((rem >> 5) & 31) * 32;
        const int tx = tid & 31, ty = tid >> 5;    // 32 x 8
        const float* W = (z == 0) ? W0 : (z == 1) ? W1 : (z == 2) ? W2 : W3;
        bf16_t* out = Wt + ((size_t)z << 20);
#pragma unroll
        for (int i = 0; i < 32; i += 8)
            t[ty + i][tx] = W[(size_t)(k0 + ty + i) * DMODEL + n0 + tx];
        __syncthreads();
#pragma unroll
        for (int i = 0; i < 32; i += 8)
            out[(size_t)(n0 + ty + i) * DMODEL + k0 + tx] = (bf16_t)t[tx][ty + i];
    } else {                                       // rope table (256 blocks)
        int idx = (id - 8192) * 256 + tid;         // SEQ*32
        int j = idx & 31, s = idx >> 5;
        float inv = powf(10000.0f, -(float)j / 32.0f);
        float ang = (float)s * inv;
        cs[idx] = make_float2(cosf(ang), sinf(ang));
    }
}

// ---------------- GEMM core: 128 x (NF*32) tile, BK=32, 3-deep prefetch ----------------
template<int NF>
__device__ __forceinline__ void gemm_core(const bf16_t* __restrict__ A,
                                          const bf16_t* __restrict__ Bt,
                                          int m0, int n0,
                                          bf16_t* As, bf16_t* Bs,
                                          f32x4 (&acc)[4][NF]) {
    const int tid = threadIdx.x, lane = tid & 63, wid = tid >> 6;
    const int wr = wid >> 1, wc = wid & 1;
    const int lm = lane & 15, lq = lane >> 4;
    constexpr int BROWS = NF * 32;
    constexpr int NT = DMODEL / 32;

    const int r_in = lane >> 2;                                  // 0..15
    const int csw  = (((lane & 3) ^ ((lane >> 3) & 3)) << 3);    // src col (elems)
    const bf16_t* Ag = A  + (size_t)(m0 + 32 * wid + r_in) * DMODEL + csw;
    const bf16_t* Bg = Bt + (size_t)(n0 + (NF * 8) * wid + r_in) * DMODEL + csw;
    const int cswr = ((lq ^ ((lm >> 1) & 3)) << 4);

    auto stage = [&](int t, int buf) {
        const int k0 = t * 32;
        bf16_t* a = As + buf * (128 * 32) + 32 * wid * 32;
        bf16_t* b = Bs + buf * (BROWS * 32) + (NF * 8) * wid * 32;
        GLOAD16(Ag + k0,               a);
        GLOAD16(Ag + 16 * DMODEL + k0, a + 16 * 32);
        GLOAD16(Bg + k0,               b);
        if constexpr (NF == 4) GLOAD16(Bg + 16 * DMODEL + k0, b + 16 * 32);
    };

    stage(0, 0);
    stage(1, 1);
    int cb = 0;
    for (int t = 0; t < NT; ++t) {
        if (t + 2 < NT) {
            int sb = cb + 2; if (sb >= 3) sb -= 3;
            stage(t + 2, sb);
            if constexpr (NF == 4) asm volatile("s_waitcnt vmcnt(8)" ::: "memory");
            else                   asm volatile("s_waitcnt vmcnt(6)" ::: "memory");
        } else if (t + 1 < NT) {
            if constexpr (NF == 4) asm volatile("s_waitcnt vmcnt(4)" ::: "memory");
            else                   asm volatile("s_waitcnt vmcnt(3)" ::: "memory");
        } else {
            asm volatile("s_waitcnt vmcnt(0)" ::: "memory");
        }
        __builtin_amdgcn_s_barrier();

        const char* pAs = (const char*)(As + cb * (128 * 32));
        const char* pBs = (const char*)(Bs + cb * (BROWS * 32));
        bf16x8 af[4], bfr[NF];
#pragma unroll
        for (int mf = 0; mf < 4; ++mf)
            af[mf] = *reinterpret_cast<const bf16x8*>(pAs + (wr * 64 + mf * 16 + lm) * 64 + cswr);
#pragma unroll
        for (int nf = 0; nf < NF; ++nf)
            bfr[nf] = *reinterpret_cast<const bf16x8*>(pBs + (wc * (NF * 16) + nf * 16 + lm) * 64 + cswr);
#pragma unroll
        for (int mf = 0; mf < 4; ++mf)
#pragma unroll
            for (int nf = 0; nf < NF; ++nf)
                acc[mf][nf] = __builtin_amdgcn_mfma_f32_16x16x32_bf16(af[mf], bfr[nf], acc[mf][nf], 0, 0, 0);

        asm volatile("" ::: "memory");
        __builtin_amdgcn_s_barrier();
        if (++cb == 3) cb = 0;
    }
}

// ---------------- fused QKV projections: 768 blocks (XCD-swizzled) ----------------
__global__ __launch_bounds__(256)
void gemm_qkv_kernel(const bf16_t* __restrict__ xb, const bf16_t* __restrict__ wtqk,
                     const bf16_t* __restrict__ wtv,
                     const float* __restrict__ bq, const float* __restrict__ bk,
                     const float* __restrict__ bv,
                     bf16_t* __restrict__ qb, bf16_t* __restrict__ kb,
                     bf16_t* __restrict__ vtb, const float2* __restrict__ cs) {
    __shared__ bf16_t As[3 * 128 * 32];
    __shared__ bf16_t Bs[3 * 128 * 32];
    const int tid = threadIdx.x, lane = tid & 63, wid = tid >> 6;
    const int wr = wid >> 1, wc = wid & 1;
    const int lm = lane & 15, lq = lane >> 4;
    const int orig = blockIdx.x;
    const int id = (orig & 7) * 96 + (orig >> 3);   // bijective XCD swizzle (768 = 8*96)
    f32x4 acc[4][4] = {};

    if (id < 512) {
        const int m0 = (id >> 4) * 128, n0 = (id & 15) * 128;
        gemm_core<4>(xb, wtqk, m0, n0, As, Bs, acc);
        const bool is_k = (n0 >= 1024);
        const float* bs = is_k ? bk : bq;
        bf16_t* C = is_k ? kb : qb;
        const int cb = (is_k ? n0 - 1024 : n0) + wc * 64;
        const float b0 = bs[cb + lm],      b1 = bs[cb + 16 + lm];
        const float b2 = bs[cb + 32 + lm], b3 = bs[cb + 48 + lm];
#pragma unroll
        for (int mf = 0; mf < 4; ++mf)
#pragma unroll
            for (int i = 0; i < 4; ++i) {
                const int row = m0 + wr * 64 + mf * 16 + lq * 4 + i;
                const int s = row & (SEQ - 1);
                const float2 cs0 = cs[s * 32 + lm];
                const float2 cs1 = cs[s * 32 + 16 + lm];
                const float a0 = acc[mf][0][i] + b0, a1 = acc[mf][1][i] + b1;
                const float a2 = acc[mf][2][i] + b2, a3 = acc[mf][3][i] + b3;
                bf16_t* p = C + (size_t)row * DMODEL + cb;
                p[lm]      = (bf16_t)(a0 * cs0.x - a2 * cs0.y);
                p[16 + lm] = (bf16_t)(a1 * cs1.x - a3 * cs1.y);
                p[32 + lm] = (bf16_t)(a2 * cs0.x + a0 * cs0.y);
                p[48 + lm] = (bf16_t)(a3 * cs1.x + a1 * cs1.y);
            }
    } else {
        const int id2 = id - 512;
        const int m0 = (id2 & 7) * 128, n0 = (id2 >> 3) * 128;
        gemm_core<4>(wtv, xb, m0, n0, As, Bs, acc);
#pragma unroll
        for (int mf = 0; mf < 4; ++mf)
#pragma unroll
            for (int i = 0; i < 4; ++i) {
                const int row = m0 + wr * 64 + mf * 16 + lq * 4 + i;
                const float brow = bv[row];
#pragma unroll
                for (int nf = 0; nf < 4; ++nf) {
                    const int col = n0 + wc * 64 + nf * 16 + lm;
                    vtb[(size_t)row * 4096 + col] = (bf16_t)(acc[mf][nf][i] + brow);
                }
            }
    }
}

// ---------------- output projection: 128x64 tile, 512 blocks (XCD-swizzled) ----------
__global__ __launch_bounds__(256)
void gemm_out_kernel(const bf16_t* __restrict__ A, const bf16_t* __restrict__ Bt,
                     const float* __restrict__ bias, float* __restrict__ C) {
    __shared__ bf16_t As[3 * 128 * 32];
    __shared__ bf16_t Bs[3 * 64 * 32];
    const int tid = threadIdx.x, lane = tid & 63, wid = tid >> 6;
    const int wr = wid >> 1, wc = wid & 1;
    const int lm = lane & 15, lq = lane >> 4;
    const int orig = blockIdx.x;
    const int id = (orig & 7) * 64 + (orig >> 3);   // bijective XCD swizzle (512 = 8*64)
    const int m0 = (id >> 4) * 128, n0 = (id & 15) * 64;
    f32x4 acc[4][2] = {};
    gemm_core<2>(A, Bt, m0, n0, As, Bs, acc);
#pragma unroll
    for (int nf = 0; nf < 2; ++nf) {
        const int col = n0 + wc * 32 + nf * 16 + lm;
        const float bcol = bias[col];
#pragma unroll
        for (int mf = 0; mf < 4; ++mf)
#pragma unroll
            for (int i = 0; i < 4; ++i) {
                const int row = m0 + wr * 64 + mf * 16 + lq * 4 + i;
                C[(size_t)row * DMODEL + col] = acc[mf][nf][i] + bcol;
            }
    }
}

// ---------------- flash attention: LDS-staged, software-pipelined one KV tile ahead ----
// 4 waves x 32 q-rows, in-register P (sigma-permuted K staging), ones-MFMA denom,
// static max in acc-init. 4 LDS buffers; per iter: stage(t+2) -> vmcnt(4) -> barrier ->
// QK[t+1] (MFMA) || softmax[t] (VALU) -> PV[t]. One barrier per iter.
__global__ __launch_bounds__(256)
void attn_kernel(const bf16_t* __restrict__ q, const bf16_t* __restrict__ k,
                 const bf16_t* __restrict__ vt, bf16_t* __restrict__ attnout) {
    const int tid = threadIdx.x, lane = tid & 63, wid = tid >> 6;
    const int lm = lane & 15, lq = lane >> 4;
    const int bh = blockIdx.y, b = bh >> 4, h = bh & 15;
    const int qrow0 = blockIdx.x * 128 + wid * 32;
    const float MS = 20.0f;
    constexpr int NT = SEQ / 64;     // 32 KV tiles

    __shared__ bf16_t Ks[4][64][64];
    __shared__ bf16_t Vs[4][64][64];

    // Q fragments (B-operand), 2 sets, pre-scaled by (1/sqrt(64))*log2(e)
    const bf16_t* qA = q + ((size_t)(b * SEQ + qrow0 + lm) * NHEAD + h) * DK + lq * 8;
    const bf16_t* qB = qA + (size_t)16 * NHEAD * DK;
    bf16x8 aqA0 = *reinterpret_cast<const bf16x8*>(qA);
    bf16x8 aqA1 = *reinterpret_cast<const bf16x8*>(qA + 32);
    bf16x8 aqB0 = *reinterpret_cast<const bf16x8*>(qB);
    bf16x8 aqB1 = *reinterpret_cast<const bf16x8*>(qB + 32);
#pragma unroll
    for (int j = 0; j < 8; ++j) {
        aqA0[j] = (bf16_t)((float)aqA0[j] * 0.18033688f);
        aqA1[j] = (bf16_t)((float)aqA1[j] * 0.18033688f);
        aqB0[j] = (bf16_t)((float)aqB0[j] * 0.18033688f);
        aqB1[j] = (bf16_t)((float)aqB1[j] * 0.18033688f);
    }
    const bf16_t one = (bf16_t)1.0f;
    const bf16x8 ones = { one, one, one, one, one, one, one, one };
    const f32x4 cinit = { -MS, -MS, -MS, -MS };

    // staging addresses (sigma row permutation folded into K source row)
    const int r0   = 8 * wid + (lane >> 3);                 // LDS row, chunk0 (0..31)
    const int scol = (((lane & 7) ^ (lane >> 3)) << 3);     // swizzled src col (elems)
    const int sig  = ((r0 >> 2) & 3) * 8 + ((r0 >> 4) & 1) * 4 + (r0 & 3);
    const bf16_t* kg = k  + ((size_t)(b * SEQ + sig) * NHEAD + h) * DK + scol;
    const bf16_t* vg = vt + ((size_t)(h * DK + r0)) * 4096 + (size_t)b * SEQ + scol;
    const size_t kstep = (size_t)NHEAD * DK;
    const char* ksb = (const char*)Ks;
    const char* vsb = (const char*)Vs;
    const int c0 = (lq << 4) ^ ((lm & 7) << 4);
    const int rowb = lm * 128;

    f32x4 OA[4] = {}, OB[4] = {};
    f32x4 olA = {}, olB = {};

    auto stage = [&](int buf, int kb) {
        GLOAD16(kg + (size_t)kb * kstep,        &Ks[buf][8 * wid][0]);
        GLOAD16(kg + (size_t)(kb + 32) * kstep, &Ks[buf][32 + 8 * wid][0]);
        GLOAD16(vg + kb,                        &Vs[buf][8 * wid][0]);
        GLOAD16(vg + (size_t)32 * 4096 + kb,    &Vs[buf][32 + 8 * wid][0]);
    };
    auto qk = [&](int buf, f32x4 (&sA)[4], f32x4 (&sB)[4]) {
        const char* kt = ksb + buf * 8192;
        __builtin_amdgcn_s_setprio(1);
#pragma unroll
        for (int t = 0; t < 4; ++t) {
            bf16x8 a0 = *reinterpret_cast<const bf16x8*>(kt + t * 2048 + rowb + c0);
            bf16x8 a1 = *reinterpret_cast<const bf16x8*>(kt + t * 2048 + rowb + (c0 ^ 64));
            f32x4 xA = __builtin_amdgcn_mfma_f32_16x16x32_bf16(a0, aqA0, cinit, 0, 0, 0);
            xA = __builtin_amdgcn_mfma_f32_16x16x32_bf16(a1, aqA1, xA, 0, 0, 0);
            f32x4 xB = __builtin_amdgcn_mfma_f32_16x16x32_bf16(a0, aqB0, cinit, 0, 0, 0);
            xB = __builtin_amdgcn_mfma_f32_16x16x32_bf16(a1, aqB1, xB, 0, 0, 0);
            sA[t] = xA; sB[t] = xB;
        }
        __builtin_amdgcn_s_setprio(0);
    };

    // prologue: stage tiles 0,1; compute QK[0]
    stage(0, 0);
    stage(1, 64);
    asm volatile("s_waitcnt vmcnt(4)" ::: "memory");
    __builtin_amdgcn_s_barrier();
    asm volatile("" ::: "memory");
    f32x4 stA[4], stB[4];
    qk(0, stA, stB);

    for (int t = 0; t < NT; ++t) {
        const int kb = t * 64;
        // stage tile t+2 into buffer (t+2)&3 (held tile t-2; reads done pre-barrier[t-1])
        if (t + 2 < NT) stage((t + 2) & 3, kb + 128);
        if (t + 1 < NT) {
            if (t + 2 < NT) asm volatile("s_waitcnt vmcnt(4)" ::: "memory");
            else            asm volatile("s_waitcnt vmcnt(0)" ::: "memory");
            __builtin_amdgcn_s_barrier();     // tile t+1 visible; iter t-1 reads done
            asm volatile("" ::: "memory");
        }

        // QK[t+1] (MFMA pipe) — independent of softmax[t] (VALU pipe)
        f32x4 nA[4], nB[4];
        if (t + 1 < NT) qk((t + 1) & 3, nA, nB);

        // softmax[t]: exp2 + pack, P already in PV B-frag order
        bf16x8 paA0, paA1, paB0, paB1;
#pragma unroll
        for (int u = 0; u < 2; ++u)
#pragma unroll
            for (int i = 0; i < 4; ++i) {
                paA0[4 * u + i] = (bf16_t)exp2_hw(stA[u][i]);
                paA1[4 * u + i] = (bf16_t)exp2_hw(stA[u + 2][i]);
                paB0[4 * u + i] = (bf16_t)exp2_hw(stB[u][i]);
                paB1[4 * u + i] = (bf16_t)exp2_hw(stB[u + 2][i]);
            }

        // PV[t] from V buffer t&3
        const char* vtl = vsb + (t & 3) * 8192;
        __builtin_amdgcn_s_setprio(1);
#pragma unroll
        for (int nf = 0; nf < 4; ++nf) {
            bf16x8 v0 = *reinterpret_cast<const bf16x8*>(vtl + nf * 2048 + rowb + c0);
            bf16x8 v1 = *reinterpret_cast<const bf16x8*>(vtl + nf * 2048 + rowb + (c0 ^ 64));
            f32x4 oA = OA[nf], oB = OB[nf];
            oA = __builtin_amdgcn_mfma_f32_16x16x32_bf16(v0, paA0, oA, 0, 0, 0);
            oA = __builtin_amdgcn_mfma_f32_16x16x32_bf16(v1, paA1, oA, 0, 0, 0);
            oB = __builtin_amdgcn_mfma_f32_16x16x32_bf16(v0, paB0, oB, 0, 0, 0);
            oB = __builtin_amdgcn_mfma_f32_16x16x32_bf16(v1, paB1, oB, 0, 0, 0);
            OA[nf] = oA; OB[nf] = oB;
        }
        olA = __builtin_amdgcn_mfma_f32_16x16x32_bf16(ones, paA0, olA, 0, 0, 0);
        olA = __builtin_amdgcn_mfma_f32_16x16x32_bf16(ones, paA1, olA, 0, 0, 0);
        olB = __builtin_amdgcn_mfma_f32_16x16x32_bf16(ones, paB0, olB, 0, 0, 0);
        olB = __builtin_amdgcn_mfma_f32_16x16x32_bf16(ones, paB1, olB, 0, 0, 0);
        __builtin_amdgcn_s_setprio(0);

        if (t + 1 < NT) {
#pragma unroll
            for (int i = 0; i < 4; ++i) { stA[i] = nA[i]; stB[i] = nB[i]; }
        }
    }

    const float invA = 1.0f / olA[0];
    const float invB = 1.0f / olB[0];
    bf16_t* obA = attnout + ((size_t)(b * SEQ + qrow0 + lm) * NHEAD + h) * DK;
    bf16_t* obB = obA + (size_t)16 * NHEAD * DK;
#pragma unroll
    for (int nf = 0; nf < 4; ++nf) {
        bf16x4 cA = { (bf16_t)(OA[nf][0] * invA), (bf16_t)(OA[nf][1] * invA),
                      (bf16_t)(OA[nf][2] * invA), (bf16_t)(OA[nf][3] * invA) };
        bf16x4 cB = { (bf16_t)(OB[nf][0] * invB), (bf16_t)(OB[nf][1] * invB),
                      (bf16_t)(OB[nf][2] * invB), (bf16_t)(OB[nf][3] * invB) };
        *reinterpret_cast<bf16x4*>(obA + nf * 16 + lq * 4) = cA;
        *reinterpret_cast<bf16x4*>(obB + nf * 16 + lq * 4) = cB;
    }
}

extern "C" void kernel_launch(void* const* d_in, const int* in_sizes, int n_in,
                              void* d_out, int out_size, void* d_ws, size_t ws_size,
                              hipStream_t stream) {
    const float* x  = (const float*)d_in[0];
    const float* Wq = (const float*)d_in[1];
    const float* bq = (const float*)d_in[2];
    const float* Wk = (const float*)d_in[3];
    const float* bk = (const float*)d_in[4];
    const float* Wv = (const float*)d_in[5];
    const float* bv = (const float*)d_in[6];
    const float* Wo = (const float*)d_in[7];
    const float* bo = (const float*)d_in[8];
    float* out = (float*)d_out;

    char* ws = (char*)d_ws;
    bf16_t* xb  = (bf16_t*)(ws);                       // 8MB (x bf16; reused as attn-out)
    bf16_t* wtq = (bf16_t*)(ws + ((size_t)8  << 20));  // 4 x 2MB transposed weights (q,k,v,o)
    bf16_t* wtv = wtq + (2 << 20);
    bf16_t* wto = wtq + (3 << 20);
    bf16_t* qb  = (bf16_t*)(ws + ((size_t)16 << 20));  // 8MB
    bf16_t* kb  = (bf16_t*)(ws + ((size_t)24 << 20));  // 8MB
    bf16_t* vtb = (bf16_t*)(ws + ((size_t)32 << 20));  // 8MB, [1024][4096]
    float2* csT = (float2*)(ws + ((size_t)40 << 20));  // 512KB
    bf16_t* aob = xb;

    prep_kernel<<<8448, 256, 0, stream>>>(x, xb, Wq, Wk, Wv, Wo, wtq, csT);
    gemm_qkv_kernel<<<768, 256, 0, stream>>>(xb, wtq, wtv, bq, bk, bv, qb, kb, vtb, csT);
    attn_kernel<<<dim3(16, 32), 256, 0, stream>>>(qb, kb, vtb, aob);
    gemm_out_kernel<<<512, 256, 0, stream>>>(aob, wto, bo, out);
}

// Round 10
// 122.952 us; speedup vs baseline: 1.5917x; 1.0008x over previous
//
#include <hip/hip_runtime.h>
#include <hip/hip_bf16.h>
#include <math.h>

typedef __bf16 bf16_t;
typedef bf16_t bf16x4 __attribute__((ext_vector_type(4)));
typedef bf16_t bf16x8 __attribute__((ext_vector_type(8)));
typedef float f32x4 __attribute__((ext_vector_type(4)));

#define SEQ 2048
#define BATCH 2
#define NHEAD 16
#define DK 64
#define DMODEL 1024

#define GLOAD16(gsrc, ldst)                                                        \
    __builtin_amdgcn_global_load_lds(                                              \
        (const __attribute__((address_space(1))) void*)(gsrc),                     \
        (__attribute__((address_space(3))) void*)(ldst), 16, 0, 0)

__device__ __forceinline__ float exp2_hw(float x) {
#if __has_builtin(__builtin_amdgcn_exp2f)
    return __builtin_amdgcn_exp2f(x);
#else
    float r; asm("v_exp_f32 %0, %1" : "=v"(r) : "v"(x)); return r;
#endif
}

// ---------------- fused prep: cvt x -> bf16 | transpose 4x W -> bf16 | rope table ----
__global__ __launch_bounds__(256)
void prep_kernel(const float* __restrict__ x, bf16_t* __restrict__ y,
                 const float* __restrict__ W0, const float* __restrict__ W1,
                 const float* __restrict__ W2, const float* __restrict__ W3,
                 bf16_t* __restrict__ Wt, float2* __restrict__ cs) {
    __shared__ float t[32][33];
    const int id = blockIdx.x, tid = threadIdx.x;
    if (id < 4096) {                               // cvt x (4096 blocks)
        int i = (id * 256 + tid) * 4;
        float4 v = *reinterpret_cast<const float4*>(x + i);
        bf16x4 o = { (bf16_t)v.x, (bf16_t)v.y, (bf16_t)v.z, (bf16_t)v.w };
        *reinterpret_cast<bf16x4*>(y + i) = o;
    } else if (id < 8192) {                        // transpose W (4096 blocks)
        const int id2 = id - 4096;
        const int z = id2 >> 10, rem = id2 & 1023;
        const int n0 = (rem & 31) * 32, k0 = ((rem >> 5) & 31) * 32;
        const int tx = tid & 31, ty = tid >> 5;    // 32 x 8
        const float* W = (z == 0) ? W0 : (z == 1) ? W1 : (z == 2) ? W2 : W3;
        bf16_t* out = Wt + ((size_t)z << 20);
#pragma unroll
        for (int i = 0; i < 32; i += 8)
            t[ty + i][tx] = W[(size_t)(k0 + ty + i) * DMODEL + n0 + tx];
        __syncthreads();
#pragma unroll
        for (int i = 0; i < 32; i += 8)
            out[(size_t)(n0 + ty + i) * DMODEL + k0 + tx] = (bf16_t)t[tx][ty + i];
    } else {                                       // rope table (256 blocks)
        int idx = (id - 8192) * 256 + tid;         // SEQ*32
        int j = idx & 31, s = idx >> 5;
        float inv = powf(10000.0f, -(float)j / 32.0f);
        float ang = (float)s * inv;
        cs[idx] = make_float2(cosf(ang), sinf(ang));
    }
}

// ---------------- GEMM core: 128 x (NF*32) tile, BK=32, 3-deep prefetch ----------------
template<int NF>
__device__ __forceinline__ void gemm_core(const bf16_t* __restrict__ A,
                                          const bf16_t* __restrict__ Bt,
                                          int m0, int n0,
                                          bf16_t* As, bf16_t* Bs,
                                          f32x4 (&acc)[4][NF]) {
    const int tid = threadIdx.x, lane = tid & 63, wid = tid >> 6;
    const int wr = wid >> 1, wc = wid & 1;
    const int lm = lane & 15, lq = lane >> 4;
    constexpr int BROWS = NF * 32;
    constexpr int NT = DMODEL / 32;

    const int r_in = lane >> 2;                                  // 0..15
    const int csw  = (((lane & 3) ^ ((lane >> 3) & 3)) << 3);    // src col (elems)
    const bf16_t* Ag = A  + (size_t)(m0 + 32 * wid + r_in) * DMODEL + csw;
    const bf16_t* Bg = Bt + (size_t)(n0 + (NF * 8) * wid + r_in) * DMODEL + csw;
    const int cswr = ((lq ^ ((lm >> 1) & 3)) << 4);

    auto stage = [&](int t, int buf) {
        const int k0 = t * 32;
        bf16_t* a = As + buf * (128 * 32) + 32 * wid * 32;
        bf16_t* b = Bs + buf * (BROWS * 32) + (NF * 8) * wid * 32;
        GLOAD16(Ag + k0,               a);
        GLOAD16(Ag + 16 * DMODEL + k0, a + 16 * 32);
        GLOAD16(Bg + k0,               b);
        if constexpr (NF == 4) GLOAD16(Bg + 16 * DMODEL + k0, b + 16 * 32);
    };

    stage(0, 0);
    stage(1, 1);
    int cb = 0;
    for (int t = 0; t < NT; ++t) {
        if (t + 2 < NT) {
            int sb = cb + 2; if (sb >= 3) sb -= 3;
            stage(t + 2, sb);
            if constexpr (NF == 4) asm volatile("s_waitcnt vmcnt(8)" ::: "memory");
            else                   asm volatile("s_waitcnt vmcnt(6)" ::: "memory");
        } else if (t + 1 < NT) {
            if constexpr (NF == 4) asm volatile("s_waitcnt vmcnt(4)" ::: "memory");
            else                   asm volatile("s_waitcnt vmcnt(3)" ::: "memory");
        } else {
            asm volatile("s_waitcnt vmcnt(0)" ::: "memory");
        }
        __builtin_amdgcn_s_barrier();

        const char* pAs = (const char*)(As + cb * (128 * 32));
        const char* pBs = (const char*)(Bs + cb * (BROWS * 32));
        bf16x8 af[4], bfr[NF];
#pragma unroll
        for (int mf = 0; mf < 4; ++mf)
            af[mf] = *reinterpret_cast<const bf16x8*>(pAs + (wr * 64 + mf * 16 + lm) * 64 + cswr);
#pragma unroll
        for (int nf = 0; nf < NF; ++nf)
            bfr[nf] = *reinterpret_cast<const bf16x8*>(pBs + (wc * (NF * 16) + nf * 16 + lm) * 64 + cswr);
#pragma unroll
        for (int mf = 0; mf < 4; ++mf)
#pragma unroll
            for (int nf = 0; nf < NF; ++nf)
                acc[mf][nf] = __builtin_amdgcn_mfma_f32_16x16x32_bf16(af[mf], bfr[nf], acc[mf][nf], 0, 0, 0);

        asm volatile("" ::: "memory");
        __builtin_amdgcn_s_barrier();
        if (++cb == 3) cb = 0;
    }
}

// ---------------- fused QKV projections: 768 blocks (XCD-swizzled) ----------------
__global__ __launch_bounds__(256)
void gemm_qkv_kernel(const bf16_t* __restrict__ xb, const bf16_t* __restrict__ wtqk,
                     const bf16_t* __restrict__ wtv,
                     const float* __restrict__ bq, const float* __restrict__ bk,
                     const float* __restrict__ bv,
                     bf16_t* __restrict__ qb, bf16_t* __restrict__ kb,
                     bf16_t* __restrict__ vtb, const float2* __restrict__ cs) {
    __shared__ bf16_t As[3 * 128 * 32];
    __shared__ bf16_t Bs[3 * 128 * 32];
    const int tid = threadIdx.x, lane = tid & 63, wid = tid >> 6;
    const int wr = wid >> 1, wc = wid & 1;
    const int lm = lane & 15, lq = lane >> 4;
    const int orig = blockIdx.x;
    const int id = (orig & 7) * 96 + (orig >> 3);   // bijective XCD swizzle (768 = 8*96)
    f32x4 acc[4][4] = {};

    if (id < 512) {
        const int m0 = (id >> 4) * 128, n0 = (id & 15) * 128;
        gemm_core<4>(xb, wtqk, m0, n0, As, Bs, acc);
        const bool is_k = (n0 >= 1024);
        const float* bs = is_k ? bk : bq;
        bf16_t* C = is_k ? kb : qb;
        const int cb = (is_k ? n0 - 1024 : n0) + wc * 64;
        const float b0 = bs[cb + lm],      b1 = bs[cb + 16 + lm];
        const float b2 = bs[cb + 32 + lm], b3 = bs[cb + 48 + lm];
#pragma unroll
        for (int mf = 0; mf < 4; ++mf)
#pragma unroll
            for (int i = 0; i < 4; ++i) {
                const int row = m0 + wr * 64 + mf * 16 + lq * 4 + i;
                const int s = row & (SEQ - 1);
                const float2 cs0 = cs[s * 32 + lm];
                const float2 cs1 = cs[s * 32 + 16 + lm];
                const float a0 = acc[mf][0][i] + b0, a1 = acc[mf][1][i] + b1;
                const float a2 = acc[mf][2][i] + b2, a3 = acc[mf][3][i] + b3;
                bf16_t* p = C + (size_t)row * DMODEL + cb;
                p[lm]      = (bf16_t)(a0 * cs0.x - a2 * cs0.y);
                p[16 + lm] = (bf16_t)(a1 * cs1.x - a3 * cs1.y);
                p[32 + lm] = (bf16_t)(a2 * cs0.x + a0 * cs0.y);
                p[48 + lm] = (bf16_t)(a3 * cs1.x + a1 * cs1.y);
            }
    } else {
        const int id2 = id - 512;
        const int m0 = (id2 & 7) * 128, n0 = (id2 >> 3) * 128;
        gemm_core<4>(wtv, xb, m0, n0, As, Bs, acc);
#pragma unroll
        for (int mf = 0; mf < 4; ++mf)
#pragma unroll
            for (int i = 0; i < 4; ++i) {
                const int row = m0 + wr * 64 + mf * 16 + lq * 4 + i;
                const float brow = bv[row];
#pragma unroll
                for (int nf = 0; nf < 4; ++nf) {
                    const int col = n0 + wc * 64 + nf * 16 + lm;
                    vtb[(size_t)row * 4096 + col] = (bf16_t)(acc[mf][nf][i] + brow);
                }
            }
    }
}

// ---------------- output projection: 128x64 tile, 512 blocks (XCD-swizzled) ----------
__global__ __launch_bounds__(256)
void gemm_out_kernel(const bf16_t* __restrict__ A, const bf16_t* __restrict__ Bt,
                     const float* __restrict__ bias, float* __restrict__ C) {
    __shared__ bf16_t As[3 * 128 * 32];
    __shared__ bf16_t Bs[3 * 64 * 32];
    const int tid = threadIdx.x, lane = tid & 63, wid = tid >> 6;
    const int wr = wid >> 1, wc = wid & 1;
    const int lm = lane & 15, lq = lane >> 4;
    const int orig = blockIdx.x;
    const int id = (orig & 7) * 64 + (orig >> 3);   // bijective XCD swizzle (512 = 8*64)
    const int m0 = (id >> 4) * 128, n0 = (id & 15) * 64;
    f32x4 acc[4][2] = {};
    gemm_core<2>(A, Bt, m0, n0, As, Bs, acc);
#pragma unroll
    for (int nf = 0; nf < 2; ++nf) {
        const int col = n0 + wc * 32 + nf * 16 + lm;
        const float bcol = bias[col];
#pragma unroll
        for (int mf = 0; mf < 4; ++mf)
#pragma unroll
            for (int i = 0; i < 4; ++i) {
                const int row = m0 + wr * 64 + mf * 16 + lq * 4 + i;
                C[(size_t)row * DMODEL + col] = acc[mf][nf][i] + bcol;
            }
    }
}

// ---------------- flash attention: LDS-staged, software-pipelined one KV tile ahead ----
// 4 waves x 32 q-rows, in-register P (sigma-permuted K staging), ones-MFMA denom,
// static max in acc-init. 4 LDS buffers; per iter: stage(t+2) -> vmcnt(4) -> barrier ->
// QK[t+1] (MFMA) || softmax[t] (VALU) -> PV[t]. One barrier per iter.
__global__ __launch_bounds__(256)
void attn_kernel(const bf16_t* __restrict__ q, const bf16_t* __restrict__ k,
                 const bf16_t* __restrict__ vt, bf16_t* __restrict__ attnout) {
    const int tid = threadIdx.x, lane = tid & 63, wid = tid >> 6;
    const int lm = lane & 15, lq = lane >> 4;
    const int bh = blockIdx.y, b = bh >> 4, h = bh & 15;
    const int qrow0 = blockIdx.x * 128 + wid * 32;
    const float MS = 20.0f;
    constexpr int NT = SEQ / 64;     // 32 KV tiles

    __shared__ bf16_t Ks[4][64][64];
    __shared__ bf16_t Vs[4][64][64];

    // Q fragments (B-operand), 2 sets, pre-scaled by (1/sqrt(64))*log2(e)
    const bf16_t* qA = q + ((size_t)(b * SEQ + qrow0 + lm) * NHEAD + h) * DK + lq * 8;
    const bf16_t* qB = qA + (size_t)16 * NHEAD * DK;
    bf16x8 aqA0 = *reinterpret_cast<const bf16x8*>(qA);
    bf16x8 aqA1 = *reinterpret_cast<const bf16x8*>(qA + 32);
    bf16x8 aqB0 = *reinterpret_cast<const bf16x8*>(qB);
    bf16x8 aqB1 = *reinterpret_cast<const bf16x8*>(qB + 32);
#pragma unroll
    for (int j = 0; j < 8; ++j) {
        aqA0[j] = (bf16_t)((float)aqA0[j] * 0.18033688f);
        aqA1[j] = (bf16_t)((float)aqA1[j] * 0.18033688f);
        aqB0[j] = (bf16_t)((float)aqB0[j] * 0.18033688f);
        aqB1[j] = (bf16_t)((float)aqB1[j] * 0.18033688f);
    }
    const bf16_t one = (bf16_t)1.0f;
    const bf16x8 ones = { one, one, one, one, one, one, one, one };
    const f32x4 cinit = { -MS, -MS, -MS, -MS };

    // staging addresses (sigma row permutation folded into K source row)
    const int r0   = 8 * wid + (lane >> 3);                 // LDS row, chunk0 (0..31)
    const int scol = (((lane & 7) ^ (lane >> 3)) << 3);     // swizzled src col (elems)
    const int sig  = ((r0 >> 2) & 3) * 8 + ((r0 >> 4) & 1) * 4 + (r0 & 3);
    const bf16_t* kg = k  + ((size_t)(b * SEQ + sig) * NHEAD + h) * DK + scol;
    const bf16_t* vg = vt + ((size_t)(h * DK + r0)) * 4096 + (size_t)b * SEQ + scol;
    const size_t kstep = (size_t)NHEAD * DK;
    const char* ksb = (const char*)Ks;
    const char* vsb = (const char*)Vs;
    const int c0 = (lq << 4) ^ ((lm & 7) << 4);
    const int rowb = lm * 128;

    f32x4 OA[4] = {}, OB[4] = {};
    f32x4 olA = {}, olB = {};

    auto stage = [&](int buf, int kb) {
        GLOAD16(kg + (size_t)kb * kstep,        &Ks[buf][8 * wid][0]);
        GLOAD16(kg + (size_t)(kb + 32) * kstep, &Ks[buf][32 + 8 * wid][0]);
        GLOAD16(vg + kb,                        &Vs[buf][8 * wid][0]);
        GLOAD16(vg + (size_t)32 * 4096 + kb,    &Vs[buf][32 + 8 * wid][0]);
    };
    auto qk = [&](int buf, f32x4 (&sA)[4], f32x4 (&sB)[4]) {
        const char* kt = ksb + buf * 8192;
        __builtin_amdgcn_s_setprio(1);
#pragma unroll
        for (int t = 0; t < 4; ++t) {
            bf16x8 a0 = *reinterpret_cast<const bf16x8*>(kt + t * 2048 + rowb + c0);
            bf16x8 a1 = *reinterpret_cast<const bf16x8*>(kt + t * 2048 + rowb + (c0 ^ 64));
            f32x4 xA = __builtin_amdgcn_mfma_f32_16x16x32_bf16(a0, aqA0, cinit, 0, 0, 0);
            xA = __builtin_amdgcn_mfma_f32_16x16x32_bf16(a1, aqA1, xA, 0, 0, 0);
            f32x4 xB = __builtin_amdgcn_mfma_f32_16x16x32_bf16(a0, aqB0, cinit, 0, 0, 0);
            xB = __builtin_amdgcn_mfma_f32_16x16x32_bf16(a1, aqB1, xB, 0, 0, 0);
            sA[t] = xA; sB[t] = xB;
        }
        __builtin_amdgcn_s_setprio(0);
    };

    // prologue: stage tiles 0,1; compute QK[0]
    stage(0, 0);
    stage(1, 64);
    asm volatile("s_waitcnt vmcnt(4)" ::: "memory");
    __builtin_amdgcn_s_barrier();
    asm volatile("" ::: "memory");
    f32x4 stA[4], stB[4];
    qk(0, stA, stB);

    for (int t = 0; t < NT; ++t) {
        const int kb = t * 64;
        // stage tile t+2 into buffer (t+2)&3 (held tile t-2; reads done pre-barrier[t-1])
        if (t + 2 < NT) stage((t + 2) & 3, kb + 128);
        if (t + 1 < NT) {
            if (t + 2 < NT) asm volatile("s_waitcnt vmcnt(4)" ::: "memory");
            else            asm volatile("s_waitcnt vmcnt(0)" ::: "memory");
            __builtin_amdgcn_s_barrier();     // tile t+1 visible; iter t-1 reads done
            asm volatile("" ::: "memory");
        }

        // QK[t+1] (MFMA pipe) — independent of softmax[t] (VALU pipe)
        f32x4 nA[4], nB[4];
        if (t + 1 < NT) qk((t + 1) & 3, nA, nB);

        // softmax[t]: exp2 + pack, P already in PV B-frag order
        bf16x8 paA0, paA1, paB0, paB1;
#pragma unroll
        for (int u = 0; u < 2; ++u)
#pragma unroll
            for (int i = 0; i < 4; ++i) {
                paA0[4 * u + i] = (bf16_t)exp2_hw(stA[u][i]);
                paA1[4 * u + i] = (bf16_t)exp2_hw(stA[u + 2][i]);
                paB0[4 * u + i] = (bf16_t)exp2_hw(stB[u][i]);
                paB1[4 * u + i] = (bf16_t)exp2_hw(stB[u + 2][i]);
            }

        // PV[t] from V buffer t&3
        const char* vtl = vsb + (t & 3) * 8192;
        __builtin_amdgcn_s_setprio(1);
#pragma unroll
        for (int nf = 0; nf < 4; ++nf) {
            bf16x8 v0 = *reinterpret_cast<const bf16x8*>(vtl + nf * 2048 + rowb + c0);
            bf16x8 v1 = *reinterpret_cast<const bf16x8*>(vtl + nf * 2048 + rowb + (c0 ^ 64));
            f32x4 oA = OA[nf], oB = OB[nf];
            oA = __builtin_amdgcn_mfma_f32_16x16x32_bf16(v0, paA0, oA, 0, 0, 0);
            oA = __builtin_amdgcn_mfma_f32_16x16x32_bf16(v1, paA1, oA, 0, 0, 0);
            oB = __builtin_amdgcn_mfma_f32_16x16x32_bf16(v0, paB0, oB, 0, 0, 0);
            oB = __builtin_amdgcn_mfma_f32_16x16x32_bf16(v1, paB1, oB, 0, 0, 0);
            OA[nf] = oA; OB[nf] = oB;
        }
        olA = __builtin_amdgcn_mfma_f32_16x16x32_bf16(ones, paA0, olA, 0, 0, 0);
        olA = __builtin_amdgcn_mfma_f32_16x16x32_bf16(ones, paA1, olA, 0, 0, 0);
        olB = __builtin_amdgcn_mfma_f32_16x16x32_bf16(ones, paB0, olB, 0, 0, 0);
        olB = __builtin_amdgcn_mfma_f32_16x16x32_bf16(ones, paB1, olB, 0, 0, 0);
        __builtin_amdgcn_s_setprio(0);

        if (t + 1 < NT) {
#pragma unroll
            for (int i = 0; i < 4; ++i) { stA[i] = nA[i]; stB[i] = nB[i]; }
        }
    }

    const float invA = 1.0f / olA[0];
    const float invB = 1.0f / olB[0];
    bf16_t* obA = attnout + ((size_t)(b * SEQ + qrow0 + lm) * NHEAD + h) * DK;
    bf16_t* obB = obA + (size_t)16 * NHEAD * DK;
#pragma unroll
    for (int nf = 0; nf < 4; ++nf) {
        bf16x4 cA = { (bf16_t)(OA[nf][0] * invA), (bf16_t)(OA[nf][1] * invA),
                      (bf16_t)(OA[nf][2] * invA), (bf16_t)(OA[nf][3] * invA) };
        bf16x4 cB = { (bf16_t)(OB[nf][0] * invB), (bf16_t)(OB[nf][1] * invB),
                      (bf16_t)(OB[nf][2] * invB), (bf16_t)(OB[nf][3] * invB) };
        *reinterpret_cast<bf16x4*>(obA + nf * 16 + lq * 4) = cA;
        *reinterpret_cast<bf16x4*>(obB + nf * 16 + lq * 4) = cB;
    }
}

extern "C" void kernel_launch(void* const* d_in, const int* in_sizes, int n_in,
                              void* d_out, int out_size, void* d_ws, size_t ws_size,
                              hipStream_t stream) {
    const float* x  = (const float*)d_in[0];
    const float* Wq = (const float*)d_in[1];
    const float* bq = (const float*)d_in[2];
    const float* Wk = (const float*)d_in[3];
    const float* bk = (const float*)d_in[4];
    const float* Wv = (const float*)d_in[5];
    const float* bv = (const float*)d_in[6];
    const float* Wo = (const float*)d_in[7];
    const float* bo = (const float*)d_in[8];
    float* out = (float*)d_out;

    char* ws = (char*)d_ws;
    bf16_t* xb  = (bf16_t*)(ws);                       // 8MB (x bf16; reused as attn-out)
    bf16_t* wtq = (bf16_t*)(ws + ((size_t)8  << 20));  // 4 x 2MB transposed weights (q,k,v,o)
    bf16_t* wtv = wtq + (2 << 20);
    bf16_t* wto = wtq + (3 << 20);
    bf16_t* qb  = (bf16_t*)(ws + ((size_t)16 << 20));  // 8MB
    bf16_t* kb  = (bf16_t*)(ws + ((size_t)24 << 20));  // 8MB
    bf16_t* vtb = (bf16_t*)(ws + ((size_t)32 << 20));  // 8MB, [1024][4096]
    float2* csT = (float2*)(ws + ((size_t)40 << 20));  // 512KB
    bf16_t* aob = xb;

    prep_kernel<<<8448, 256, 0, stream>>>(x, xb, Wq, Wk, Wv, Wo, wtq, csT);
    gemm_qkv_kernel<<<768, 256, 0, stream>>>(xb, wtq, wtv, bq, bk, bv, qb, kb, vtb, csT);
    attn_kernel<<<dim3(16, 32), 256, 0, stream>>>(qb, kb, vtb, aob);
    gemm_out_kernel<<<512, 256, 0, stream>>>(aob, wto, bo, out);
}

// Round 11
// 120.766 us; speedup vs baseline: 1.6205x; 1.0181x over previous
//
#include <hip/hip_runtime.h>
#include <hip/hip_bf16.h>
#include <math.h>

typedef __bf16 bf16_t;
typedef bf16_t bf16x4 __attribute__((ext_vector_type(4)));
typedef bf16_t bf16x8 __attribute__((ext_vector_type(8)));
typedef float f32x4 __attribute__((ext_vector_type(4)));

#define SEQ 2048
#define BATCH 2
#define NHEAD 16
#define DK 64
#define DMODEL 1024

#define GLOAD16(gsrc, ldst)                                                        \
    __builtin_amdgcn_global_load_lds(                                              \
        (const __attribute__((address_space(1))) void*)(gsrc),                     \
        (__attribute__((address_space(3))) void*)(ldst), 16, 0, 0)

__device__ __forceinline__ float exp2_hw(float x) {
#if __has_builtin(__builtin_amdgcn_exp2f)
    return __builtin_amdgcn_exp2f(x);
#else
    float r; asm("v_exp_f32 %0, %1" : "=v"(r) : "v"(x)); return r;
#endif
}

// ---------------- fused prep: cvt x -> bf16 | transpose 4x W -> bf16 | rope table ----
__global__ __launch_bounds__(256)
void prep_kernel(const float* __restrict__ x, bf16_t* __restrict__ y,
                 const float* __restrict__ W0, const float* __restrict__ W1,
                 const float* __restrict__ W2, const float* __restrict__ W3,
                 bf16_t* __restrict__ Wt, float2* __restrict__ cs) {
    __shared__ float t[32][33];
    const int id = blockIdx.x, tid = threadIdx.x;
    if (id < 4096) {                               // cvt x (4096 blocks)
        int i = (id * 256 + tid) * 4;
        float4 v = *reinterpret_cast<const float4*>(x + i);
        bf16x4 o = { (bf16_t)v.x, (bf16_t)v.y, (bf16_t)v.z, (bf16_t)v.w };
        *reinterpret_cast<bf16x4*>(y + i) = o;
    } else if (id < 8192) {                        // transpose W (4096 blocks)
        const int id2 = id - 4096;
        const int z = id2 >> 10, rem = id2 & 1023;
        const int n0 = (rem & 31) * 32, k0 = ((rem >> 5) & 31) * 32;
        const int tx = tid & 31, ty = tid >> 5;    // 32 x 8
        const float* W = (z == 0) ? W0 : (z == 1) ? W1 : (z == 2) ? W2 : W3;
        bf16_t* out = Wt + ((size_t)z << 20);
#pragma unroll
        for (int i = 0; i < 32; i += 8)
            t[ty + i][tx] = W[(size_t)(k0 + ty + i) * DMODEL + n0 + tx];
        __syncthreads();
#pragma unroll
        for (int i = 0; i < 32; i += 8)
            out[(size_t)(n0 + ty + i) * DMODEL + k0 + tx] = (bf16_t)t[tx][ty + i];
    } else {                                       // rope table (256 blocks)
        int idx = (id - 8192) * 256 + tid;         // SEQ*32
        int j = idx & 31, s = idx >> 5;
        float inv = powf(10000.0f, -(float)j / 32.0f);
        float ang = (float)s * inv;
        cs[idx] = make_float2(cosf(ang), sinf(ang));
    }
}

// ---------------- GEMM core: 128 x (NF*32) tile, BK=32, 3-deep prefetch ----------------
template<int NF>
__device__ __forceinline__ void gemm_core(const bf16_t* __restrict__ A,
                                          const bf16_t* __restrict__ Bt,
                                          int m0, int n0,
                                          bf16_t* As, bf16_t* Bs,
                                          f32x4 (&acc)[4][NF]) {
    const int tid = threadIdx.x, lane = tid & 63, wid = tid >> 6;
    const int wr = wid >> 1, wc = wid & 1;
    const int lm = lane & 15, lq = lane >> 4;
    constexpr int BROWS = NF * 32;
    constexpr int NT = DMODEL / 32;

    const int r_in = lane >> 2;                                  // 0..15
    const int csw  = (((lane & 3) ^ ((lane >> 3) & 3)) << 3);    // src col (elems)
    const bf16_t* Ag = A  + (size_t)(m0 + 32 * wid + r_in) * DMODEL + csw;
    const bf16_t* Bg = Bt + (size_t)(n0 + (NF * 8) * wid + r_in) * DMODEL + csw;
    const int cswr = ((lq ^ ((lm >> 1) & 3)) << 4);

    auto stage = [&](int t, int buf) {
        const int k0 = t * 32;
        bf16_t* a = As + buf * (128 * 32) + 32 * wid * 32;
        bf16_t* b = Bs + buf * (BROWS * 32) + (NF * 8) * wid * 32;
        GLOAD16(Ag + k0,               a);
        GLOAD16(Ag + 16 * DMODEL + k0, a + 16 * 32);
        GLOAD16(Bg + k0,               b);
        if constexpr (NF == 4) GLOAD16(Bg + 16 * DMODEL + k0, b + 16 * 32);
    };

    stage(0, 0);
    stage(1, 1);
    int cb = 0;
    for (int t = 0; t < NT; ++t) {
        if (t + 2 < NT) {
            int sb = cb + 2; if (sb >= 3) sb -= 3;
            stage(t + 2, sb);
            if constexpr (NF == 4) asm volatile("s_waitcnt vmcnt(8)" ::: "memory");
            else                   asm volatile("s_waitcnt vmcnt(6)" ::: "memory");
        } else if (t + 1 < NT) {
            if constexpr (NF == 4) asm volatile("s_waitcnt vmcnt(4)" ::: "memory");
            else                   asm volatile("s_waitcnt vmcnt(3)" ::: "memory");
        } else {
            asm volatile("s_waitcnt vmcnt(0)" ::: "memory");
        }
        __builtin_amdgcn_s_barrier();

        const char* pAs = (const char*)(As + cb * (128 * 32));
        const char* pBs = (const char*)(Bs + cb * (BROWS * 32));
        bf16x8 af[4], bfr[NF];
#pragma unroll
        for (int mf = 0; mf < 4; ++mf)
            af[mf] = *reinterpret_cast<const bf16x8*>(pAs + (wr * 64 + mf * 16 + lm) * 64 + cswr);
#pragma unroll
        for (int nf = 0; nf < NF; ++nf)
            bfr[nf] = *reinterpret_cast<const bf16x8*>(pBs + (wc * (NF * 16) + nf * 16 + lm) * 64 + cswr);
#pragma unroll
        for (int mf = 0; mf < 4; ++mf)
#pragma unroll
            for (int nf = 0; nf < NF; ++nf)
                acc[mf][nf] = __builtin_amdgcn_mfma_f32_16x16x32_bf16(af[mf], bfr[nf], acc[mf][nf], 0, 0, 0);

        asm volatile("" ::: "memory");
        __builtin_amdgcn_s_barrier();
        if (++cb == 3) cb = 0;
    }
}

// ---------------- fused QKV projections: 768 blocks (XCD-swizzled) ----------------
__global__ __launch_bounds__(256)
void gemm_qkv_kernel(const bf16_t* __restrict__ xb, const bf16_t* __restrict__ wtqk,
                     const bf16_t* __restrict__ wtv,
                     const float* __restrict__ bq, const float* __restrict__ bk,
                     const float* __restrict__ bv,
                     bf16_t* __restrict__ qb, bf16_t* __restrict__ kb,
                     bf16_t* __restrict__ vtb, const float2* __restrict__ cs) {
    __shared__ bf16_t As[3 * 128 * 32];
    __shared__ bf16_t Bs[3 * 128 * 32];
    const int tid = threadIdx.x, lane = tid & 63, wid = tid >> 6;
    const int wr = wid >> 1, wc = wid & 1;
    const int lm = lane & 15, lq = lane >> 4;
    const int orig = blockIdx.x;
    const int id = (orig & 7) * 96 + (orig >> 3);   // bijective XCD swizzle (768 = 8*96)
    f32x4 acc[4][4] = {};

    if (id < 512) {
        const int m0 = (id >> 4) * 128, n0 = (id & 15) * 128;
        gemm_core<4>(xb, wtqk, m0, n0, As, Bs, acc);
        const bool is_k = (n0 >= 1024);
        const float* bs = is_k ? bk : bq;
        bf16_t* C = is_k ? kb : qb;
        const int cb = (is_k ? n0 - 1024 : n0) + wc * 64;
        const float b0 = bs[cb + lm],      b1 = bs[cb + 16 + lm];
        const float b2 = bs[cb + 32 + lm], b3 = bs[cb + 48 + lm];
#pragma unroll
        for (int mf = 0; mf < 4; ++mf)
#pragma unroll
            for (int i = 0; i < 4; ++i) {
                const int row = m0 + wr * 64 + mf * 16 + lq * 4 + i;
                const int s = row & (SEQ - 1);
                const float2 cs0 = cs[s * 32 + lm];
                const float2 cs1 = cs[s * 32 + 16 + lm];
                const float a0 = acc[mf][0][i] + b0, a1 = acc[mf][1][i] + b1;
                const float a2 = acc[mf][2][i] + b2, a3 = acc[mf][3][i] + b3;
                bf16_t* p = C + (size_t)row * DMODEL + cb;
                p[lm]      = (bf16_t)(a0 * cs0.x - a2 * cs0.y);
                p[16 + lm] = (bf16_t)(a1 * cs1.x - a3 * cs1.y);
                p[32 + lm] = (bf16_t)(a2 * cs0.x + a0 * cs0.y);
                p[48 + lm] = (bf16_t)(a3 * cs1.x + a1 * cs1.y);
            }
    } else {
        const int id2 = id - 512;
        const int m0 = (id2 & 7) * 128, n0 = (id2 >> 3) * 128;
        gemm_core<4>(wtv, xb, m0, n0, As, Bs, acc);
#pragma unroll
        for (int mf = 0; mf < 4; ++mf)
#pragma unroll
            for (int i = 0; i < 4; ++i) {
                const int row = m0 + wr * 64 + mf * 16 + lq * 4 + i;
                const float brow = bv[row];
#pragma unroll
                for (int nf = 0; nf < 4; ++nf) {
                    const int col = n0 + wc * 64 + nf * 16 + lm;
                    vtb[(size_t)row * 4096 + col] = (bf16_t)(acc[mf][nf][i] + brow);
                }
            }
    }
}

// ---------------- output projection: 128x64 tile, 512 blocks (XCD-swizzled) ----------
__global__ __launch_bounds__(256)
void gemm_out_kernel(const bf16_t* __restrict__ A, const bf16_t* __restrict__ Bt,
                     const float* __restrict__ bias, float* __restrict__ C) {
    __shared__ bf16_t As[3 * 128 * 32];
    __shared__ bf16_t Bs[3 * 64 * 32];
    const int tid = threadIdx.x, lane = tid & 63, wid = tid >> 6;
    const int wr = wid >> 1, wc = wid & 1;
    const int lm = lane & 15, lq = lane >> 4;
    const int orig = blockIdx.x;
    const int id = (orig & 7) * 64 + (orig >> 3);   // bijective XCD swizzle (512 = 8*64)
    const int m0 = (id >> 4) * 128, n0 = (id & 15) * 64;
    f32x4 acc[4][2] = {};
    gemm_core<2>(A, Bt, m0, n0, As, Bs, acc);
#pragma unroll
    for (int nf = 0; nf < 2; ++nf) {
        const int col = n0 + wc * 32 + nf * 16 + lm;
        const float bcol = bias[col];
#pragma unroll
        for (int mf = 0; mf < 4; ++mf)
#pragma unroll
            for (int i = 0; i < 4; ++i) {
                const int row = m0 + wr * 64 + mf * 16 + lq * 4 + i;
                C[(size_t)row * DMODEL + col] = acc[mf][nf][i] + bcol;
            }
    }
}

// ---------------- flash attention: pipelined + convoy-broken wave roles ----------------
// 4 waves x 32 q-rows, in-register P (sigma-permuted K staging), ones-MFMA denom,
// static max in acc-init. 4 LDS buffers, 1 barrier/iter with counted vmcnt(2):
// per iter even waves: [stageK | QK(t+1) | stageV | softmax(t) | PV(t)]
//          odd  waves: [stageK | softmax(t) | PV(t) | stageV | QK(t+1)]
// -> at any instant half the waves are on MFMA, half on VALU (convoy break).
// XCD-grouped block decode: each XCD owns 4 heads -> K/V working set 2MB fits its L2.
__global__ __launch_bounds__(256)
void attn_kernel(const bf16_t* __restrict__ q, const bf16_t* __restrict__ k,
                 const bf16_t* __restrict__ vt, bf16_t* __restrict__ attnout) {
    const int tid = threadIdx.x, lane = tid & 63, wid = tid >> 6;
    const int lm = lane & 15, lq = lane >> 4;
    // XCD-locality decode: xcd = bid&7 owns bh in [4*xcd, 4*xcd+4)
    const int bid = blockIdx.x;
    const int xcd = bid & 7, idx = bid >> 3;
    const int bh = xcd * 4 + (idx & 3), qblk = idx >> 2;
    const int b = bh >> 4, h = bh & 15;
    const int qrow0 = qblk * 128 + wid * 32;
    const float MS = 20.0f;
    constexpr int NT = SEQ / 64;     // 32 KV tiles

    __shared__ bf16_t Ks[4][64][64];
    __shared__ bf16_t Vs[4][64][64];

    // Q fragments (B-operand), 2 sets, pre-scaled by (1/sqrt(64))*log2(e)
    const bf16_t* qA = q + ((size_t)(b * SEQ + qrow0 + lm) * NHEAD + h) * DK + lq * 8;
    const bf16_t* qB = qA + (size_t)16 * NHEAD * DK;
    bf16x8 aqA0 = *reinterpret_cast<const bf16x8*>(qA);
    bf16x8 aqA1 = *reinterpret_cast<const bf16x8*>(qA + 32);
    bf16x8 aqB0 = *reinterpret_cast<const bf16x8*>(qB);
    bf16x8 aqB1 = *reinterpret_cast<const bf16x8*>(qB + 32);
#pragma unroll
    for (int j = 0; j < 8; ++j) {
        aqA0[j] = (bf16_t)((float)aqA0[j] * 0.18033688f);
        aqA1[j] = (bf16_t)((float)aqA1[j] * 0.18033688f);
        aqB0[j] = (bf16_t)((float)aqB0[j] * 0.18033688f);
        aqB1[j] = (bf16_t)((float)aqB1[j] * 0.18033688f);
    }
    const bf16_t one = (bf16_t)1.0f;
    const bf16x8 ones = { one, one, one, one, one, one, one, one };
    const f32x4 cinit = { -MS, -MS, -MS, -MS };

    // staging addresses (sigma row permutation folded into K source row)
    const int r0   = 8 * wid + (lane >> 3);                 // LDS row, chunk0 (0..31)
    const int scol = (((lane & 7) ^ (lane >> 3)) << 3);     // swizzled src col (elems)
    const int sig  = ((r0 >> 2) & 3) * 8 + ((r0 >> 4) & 1) * 4 + (r0 & 3);
    const bf16_t* kg = k  + ((size_t)(b * SEQ + sig) * NHEAD + h) * DK + scol;
    const bf16_t* vg = vt + ((size_t)(h * DK + r0)) * 4096 + (size_t)b * SEQ + scol;
    const size_t kstep = (size_t)NHEAD * DK;
    const char* ksb = (const char*)Ks;
    const char* vsb = (const char*)Vs;
    const int c0 = (lq << 4) ^ ((lm & 7) << 4);
    const int rowb = lm * 128;

    f32x4 OA[4] = {}, OB[4] = {};
    f32x4 olA = {}, olB = {};

    auto stageK = [&](int buf, int kb) {
        GLOAD16(kg + (size_t)kb * kstep,        &Ks[buf][8 * wid][0]);
        GLOAD16(kg + (size_t)(kb + 32) * kstep, &Ks[buf][32 + 8 * wid][0]);
    };
    auto stageV = [&](int buf, int kb) {
        GLOAD16(vg + kb,                        &Vs[buf][8 * wid][0]);
        GLOAD16(vg + (size_t)32 * 4096 + kb,    &Vs[buf][32 + 8 * wid][0]);
    };
    auto qk = [&](int buf, f32x4 (&sA)[4], f32x4 (&sB)[4]) {
        const char* kt = ksb + buf * 8192;
        __builtin_amdgcn_s_setprio(1);
#pragma unroll
        for (int t = 0; t < 4; ++t) {
            bf16x8 a0 = *reinterpret_cast<const bf16x8*>(kt + t * 2048 + rowb + c0);
            bf16x8 a1 = *reinterpret_cast<const bf16x8*>(kt + t * 2048 + rowb + (c0 ^ 64));
            f32x4 xA = __builtin_amdgcn_mfma_f32_16x16x32_bf16(a0, aqA0, cinit, 0, 0, 0);
            xA = __builtin_amdgcn_mfma_f32_16x16x32_bf16(a1, aqA1, xA, 0, 0, 0);
            f32x4 xB = __builtin_amdgcn_mfma_f32_16x16x32_bf16(a0, aqB0, cinit, 0, 0, 0);
            xB = __builtin_amdgcn_mfma_f32_16x16x32_bf16(a1, aqB1, xB, 0, 0, 0);
            sA[t] = xA; sB[t] = xB;
        }
        __builtin_amdgcn_s_setprio(0);
    };
    auto softmax = [&](const f32x4 (&sA)[4], const f32x4 (&sB)[4],
                       bf16x8& pA0, bf16x8& pA1, bf16x8& pB0, bf16x8& pB1) {
#pragma unroll
        for (int u = 0; u < 2; ++u)
#pragma unroll
            for (int i = 0; i < 4; ++i) {
                pA0[4 * u + i] = (bf16_t)exp2_hw(sA[u][i]);
                pA1[4 * u + i] = (bf16_t)exp2_hw(sA[u + 2][i]);
                pB0[4 * u + i] = (bf16_t)exp2_hw(sB[u][i]);
                pB1[4 * u + i] = (bf16_t)exp2_hw(sB[u + 2][i]);
            }
    };
    auto pv = [&](int buf, const bf16x8& pA0, const bf16x8& pA1,
                  const bf16x8& pB0, const bf16x8& pB1) {
        const char* vtl = vsb + buf * 8192;
        __builtin_amdgcn_s_setprio(1);
#pragma unroll
        for (int nf = 0; nf < 4; ++nf) {
            bf16x8 v0 = *reinterpret_cast<const bf16x8*>(vtl + nf * 2048 + rowb + c0);
            bf16x8 v1 = *reinterpret_cast<const bf16x8*>(vtl + nf * 2048 + rowb + (c0 ^ 64));
            f32x4 oA = OA[nf], oB = OB[nf];
            oA = __builtin_amdgcn_mfma_f32_16x16x32_bf16(v0, pA0, oA, 0, 0, 0);
            oA = __builtin_amdgcn_mfma_f32_16x16x32_bf16(v1, pA1, oA, 0, 0, 0);
            oB = __builtin_amdgcn_mfma_f32_16x16x32_bf16(v0, pB0, oB, 0, 0, 0);
            oB = __builtin_amdgcn_mfma_f32_16x16x32_bf16(v1, pB1, oB, 0, 0, 0);
            OA[nf] = oA; OB[nf] = oB;
        }
        olA = __builtin_amdgcn_mfma_f32_16x16x32_bf16(ones, pA0, olA, 0, 0, 0);
        olA = __builtin_amdgcn_mfma_f32_16x16x32_bf16(ones, pA1, olA, 0, 0, 0);
        olB = __builtin_amdgcn_mfma_f32_16x16x32_bf16(ones, pB0, olB, 0, 0, 0);
        olB = __builtin_amdgcn_mfma_f32_16x16x32_bf16(ones, pB1, olB, 0, 0, 0);
        __builtin_amdgcn_s_setprio(0);
    };

    // prologue: stage tiles 0,1 (order K0,V0,K1,V1); vmcnt(2) -> K0,V0,K1 landed
    stageK(0, 0);  stageV(0, 0);
    stageK(1, 64); stageV(1, 64);
    asm volatile("s_waitcnt vmcnt(2)" ::: "memory");
    __builtin_amdgcn_s_barrier();
    asm volatile("" ::: "memory");
    f32x4 stA[4], stB[4];
    qk(0, stA, stB);

    const bool evenw = (wid & 1) == 0;
    for (int t = 0; t < NT; ++t) {
        const int kb = t * 64;
        f32x4 nA[4], nB[4];
        bf16x8 paA0, paA1, paB0, paB1;

        if (t + 2 < NT) stageK((t + 2) & 3, kb + 128);
        if (evenw) {
            if (t + 1 < NT) qk((t + 1) & 3, nA, nB);
            if (t + 2 < NT) stageV((t + 2) & 3, kb + 128);
            softmax(stA, stB, paA0, paA1, paB0, paB1);
            pv(t & 3, paA0, paA1, paB0, paB1);
        } else {
            softmax(stA, stB, paA0, paA1, paB0, paB1);
            pv(t & 3, paA0, paA1, paB0, paB1);
            if (t + 2 < NT) stageV((t + 2) & 3, kb + 128);
            if (t + 1 < NT) qk((t + 1) & 3, nA, nB);
        }

        if (t + 1 < NT) {
            if (t + 2 < NT) asm volatile("s_waitcnt vmcnt(2)" ::: "memory");
            else            asm volatile("s_waitcnt vmcnt(0)" ::: "memory");
            __builtin_amdgcn_s_barrier();
            asm volatile("" ::: "memory");
#pragma unroll
            for (int i = 0; i < 4; ++i) { stA[i] = nA[i]; stB[i] = nB[i]; }
        }
    }

    const float invA = 1.0f / olA[0];
    const float invB = 1.0f / olB[0];
    bf16_t* obA = attnout + ((size_t)(b * SEQ + qrow0 + lm) * NHEAD + h) * DK;
    bf16_t* obB = obA + (size_t)16 * NHEAD * DK;
#pragma unroll
    for (int nf = 0; nf < 4; ++nf) {
        bf16x4 cA = { (bf16_t)(OA[nf][0] * invA), (bf16_t)(OA[nf][1] * invA),
                      (bf16_t)(OA[nf][2] * invA), (bf16_t)(OA[nf][3] * invA) };
        bf16x4 cB = { (bf16_t)(OB[nf][0] * invB), (bf16_t)(OB[nf][1] * invB),
                      (bf16_t)(OB[nf][2] * invB), (bf16_t)(OB[nf][3] * invB) };
        *reinterpret_cast<bf16x4*>(obA + nf * 16 + lq * 4) = cA;
        *reinterpret_cast<bf16x4*>(obB + nf * 16 + lq * 4) = cB;
    }
}

extern "C" void kernel_launch(void* const* d_in, const int* in_sizes, int n_in,
                              void* d_out, int out_size, void* d_ws, size_t ws_size,
                              hipStream_t stream) {
    const float* x  = (const float*)d_in[0];
    const float* Wq = (const float*)d_in[1];
    const float* bq = (const float*)d_in[2];
    const float* Wk = (const float*)d_in[3];
    const float* bk = (const float*)d_in[4];
    const float* Wv = (const float*)d_in[5];
    const float* bv = (const float*)d_in[6];
    const float* Wo = (const float*)d_in[7];
    const float* bo = (const float*)d_in[8];
    float* out = (float*)d_out;

    char* ws = (char*)d_ws;
    bf16_t* xb  = (bf16_t*)(ws);                       // 8MB (x bf16; reused as attn-out)
    bf16_t* wtq = (bf16_t*)(ws + ((size_t)8  << 20));  // 4 x 2MB transposed weights (q,k,v,o)
    bf16_t* wtv = wtq + (2 << 20);
    bf16_t* wto = wtq + (3 << 20);
    bf16_t* qb  = (bf16_t*)(ws + ((size_t)16 << 20));  // 8MB
    bf16_t* kb  = (bf16_t*)(ws + ((size_t)24 << 20));  // 8MB
    bf16_t* vtb = (bf16_t*)(ws + ((size_t)32 << 20));  // 8MB, [1024][4096]
    float2* csT = (float2*)(ws + ((size_t)40 << 20));  // 512KB
    bf16_t* aob = xb;

    prep_kernel<<<8448, 256, 0, stream>>>(x, xb, Wq, Wk, Wv, Wo, wtq, csT);
    gemm_qkv_kernel<<<768, 256, 0, stream>>>(xb, wtq, wtv, bq, bk, bv, qb, kb, vtb, csT);
    attn_kernel<<<512, 256, 0, stream>>>(qb, kb, vtb, aob);
    gemm_out_kernel<<<512, 256, 0, stream>>>(aob, wto, bo, out);
}